// Round 1
// baseline (119.898 us; speedup 1.0000x reference)
//
#include <hip/hip_runtime.h>
#include <math.h>

constexpr int H_ = 180, W_ = 320, RF_ = 16, K_ = 20, T_ = 400;
constexpr int NWIN = T_ - K_ + 1;   // 381
constexpr int PW   = W_ + 2 * RF_;  // 352 (padded width used by rf_indices)
constexpr float ALPHA = 50.0f, BETA = 1.0f, GAMMA = 0.0f;

__device__ inline float wave_sum(float v) {
#pragma unroll
    for (int off = 1; off < 64; off <<= 1)
        v += __shfl_xor(v, off, 64);
    return v;
}

// ---------------------------------------------------------------------------
// Kernel 0: factorize w (K x 256) into temporal[K] (x) spatial[256].
// w is constructed as an exact rank-1 outer product (temporal ⊗ spatial / norm),
// so a least-squares projection onto the largest row recovers it to ~1e-7 rel.
// Single block of 64 threads; negligible cost.
// ---------------------------------------------------------------------------
__global__ void factorize_kernel(const float* __restrict__ w,
                                 float* __restrict__ spatial,   // 256
                                 float* __restrict__ temporal)  // K
{
    int l = threadIdx.x;  // 0..63
    // find row with max sum-of-squares (max |temporal[k]|) — robust pivot
    float best = -1.0f;
    int k0 = 0;
    for (int k = 0; k < K_; ++k) {
        float s = 0.0f;
#pragma unroll
        for (int j = 0; j < 4; ++j) {
            float v = w[k * 256 + l + j * 64];
            s = fmaf(v, v, s);
        }
        s = wave_sum(s);  // butterfly: all lanes hold total
        if (s > best) { best = s; k0 = k; }
    }
    // spatial := w[k0, :]
#pragma unroll
    for (int j = 0; j < 4; ++j)
        spatial[l + j * 64] = w[k0 * 256 + l + j * 64];
    float inv_s2 = 1.0f / best;
    // temporal[k] := <w[k,:], spatial> / <spatial, spatial>
    for (int k = 0; k < K_; ++k) {
        float d = 0.0f;
#pragma unroll
        for (int j = 0; j < 4; ++j)
            d = fmaf(w[k * 256 + l + j * 64], w[k0 * 256 + l + j * 64], d);
        d = wave_sum(d);
        if (l == 0) temporal[k] = d * inv_s2;
    }
}

// ---------------------------------------------------------------------------
// Kernel 1: y[n, t] = sum_p x_patch[t, n, p] * spatial[p]
// One wave per (n, t): lane l covers pixels (r0 + i*4 + (l>>4), c0 + (l&15)),
// i = 0..3  -> each wave-load = 4 contiguous 64B row segments (coalesced).
// Border RFs handled by per-lane predication (reference zero-pads).
// Grid: (N, 2) x 256 threads; each wave owns t = slot (mod 8), unrolled x2.
// ---------------------------------------------------------------------------
__global__ __launch_bounds__(256) void stage1_kernel(
    const float* __restrict__ x, const int* __restrict__ rf,
    const float* __restrict__ spatial, float* __restrict__ y, int N)
{
    int lane = threadIdx.x & 63;
    int wid  = threadIdx.x >> 6;
    int n = blockIdx.x;
    if (n >= N) return;

    int base = rf[n * 256];          // = v*PW + h (first padded index)
    int r0 = base / PW - RF_;        // top row in unpadded frame (may be <0)
    int c0 = base % PW - RF_;        // left col in unpadded frame (may be <0)

    // per-lane spatial weights: p = i*64 + lane
    float w0 = spatial[lane];
    float w1 = spatial[lane + 64];
    float w2 = spatial[lane + 128];
    float w3 = spatial[lane + 192];

    int dx = lane & 15;
    int dy = lane >> 4;
    int c = c0 + dx;
    bool cok = (c >= 0) & (c < W_);

    int  ridx[4];
    bool ok[4];
#pragma unroll
    for (int i = 0; i < 4; ++i) {
        int r = r0 + i * 4 + dy;
        ok[i]  = cok & (r >= 0) & (r < H_);
        ridx[i] = r * W_ + c;  // only used when ok[i]
    }

    int slot = blockIdx.y * 4 + wid;  // 0..7
    // t = slot, slot+8, ..., exactly 50 frames; unroll 2 for ILP.
    for (int t = slot; t < T_; t += 16) {
        const float* xa = x + (size_t)t * (H_ * W_);
        const float* xb = xa + (size_t)8 * (H_ * W_);
        float acca = 0.0f, accb = 0.0f;
#pragma unroll
        for (int i = 0; i < 4; ++i) {
            float wv = (i == 0) ? w0 : (i == 1) ? w1 : (i == 2) ? w2 : w3;
            float va = ok[i] ? xa[ridx[i]] : 0.0f;
            float vb = ok[i] ? xb[ridx[i]] : 0.0f;
            acca = fmaf(va, wv, acca);
            accb = fmaf(vb, wv, accb);
        }
#pragma unroll
        for (int off = 1; off < 64; off <<= 1) {
            acca += __shfl_xor(acca, off, 64);
            accb += __shfl_xor(accb, off, 64);
        }
        if (lane == 0) {
            y[n * T_ + t]     = acca;
            y[n * T_ + t + 8] = accb;
        }
    }
}

// ---------------------------------------------------------------------------
// Kernel 2: out[n, t0] = ALPHA * softplus(BETA * (sum_k y[n, t0+k]*temporal[k]
//                                                  - GAMMA))
// One block per neuron, thread per t0. Stable softplus = logaddexp(z, 0).
// ---------------------------------------------------------------------------
__global__ void stage2_kernel(const float* __restrict__ y,
                              const float* __restrict__ temporal,
                              float* __restrict__ out, int N)
{
    __shared__ float tw[K_];
    if (threadIdx.x < K_) tw[threadIdx.x] = temporal[threadIdx.x];
    __syncthreads();

    int n  = blockIdx.x;
    int t0 = threadIdx.x;
    if (n >= N || t0 >= NWIN) return;

    const float* yn = y + n * T_;
    float g = 0.0f;
#pragma unroll
    for (int k = 0; k < K_; ++k)
        g = fmaf(yn[t0 + k], tw[k], g);

    float z = BETA * (g - GAMMA);
    float sp = fmaxf(z, 0.0f) + log1pf(expf(-fabsf(z)));
    out[n * NWIN + t0] = ALPHA * sp;
}

// ---------------------------------------------------------------------------
extern "C" void kernel_launch(void* const* d_in, const int* in_sizes, int n_in,
                              void* d_out, int out_size, void* d_ws, size_t ws_size,
                              hipStream_t stream)
{
    const float* x  = (const float*)d_in[0];  // (T, H, W) f32
    const float* w  = (const float*)d_in[1];  // (K*RF*RF,) f32
    const int*   rf = (const int*)d_in[2];    // (N, 256) i32

    int N = in_sizes[2] / (RF_ * RF_);

    float* spatial  = (float*)d_ws;           // 256
    float* temporal = spatial + 256;          // 20 (pad to 512 total)
    float* y        = spatial + 512;          // N * T

    factorize_kernel<<<1, 64, 0, stream>>>(w, spatial, temporal);
    stage1_kernel<<<dim3(N, 2), 256, 0, stream>>>(x, rf, spatial, y, N);
    stage2_kernel<<<N, 384, 0, stream>>>(y, temporal, (float*)d_out, N);
}

// Round 2
// 62.384 us; speedup vs baseline: 1.9219x; 1.9219x over previous
//
#include <hip/hip_runtime.h>
#include <math.h>

constexpr int H_ = 180, W_ = 320, RF_ = 16, K_ = 20, T_ = 400;
constexpr int NWIN = T_ - K_ + 1;   // 381
constexpr int PW   = W_ + 2 * RF_;  // 352 (padded width used by rf_indices)
constexpr float ALPHA = 50.0f, BETA = 1.0f, GAMMA = 0.0f;
constexpr int NXCD = 8;
constexpr int TPAIRS = T_ / 2;          // 200
constexpr int TP_PER_XCD = TPAIRS / NXCD;  // 25

__device__ inline float wave_sum(float v) {
#pragma unroll
    for (int off = 1; off < 64; off <<= 1)
        v += __shfl_xor(v, off, 64);
    return v;
}

// ---------------------------------------------------------------------------
// Kernel 0: factorize w (K x 256) into temporal[K] (x) spatial[256].
// w is an exact rank-1 outer product (temporal ⊗ spatial / norm); LS-project
// onto the largest row. Single 64-thread block; negligible.
// ---------------------------------------------------------------------------
__global__ void factorize_kernel(const float* __restrict__ w,
                                 float* __restrict__ spatial,   // 256
                                 float* __restrict__ temporal)  // K
{
    int l = threadIdx.x;  // 0..63
    float best = -1.0f;
    int k0 = 0;
    for (int k = 0; k < K_; ++k) {
        float s = 0.0f;
#pragma unroll
        for (int j = 0; j < 4; ++j) {
            float v = w[k * 256 + l + j * 64];
            s = fmaf(v, v, s);
        }
        s = wave_sum(s);
        if (s > best) { best = s; k0 = k; }
    }
#pragma unroll
    for (int j = 0; j < 4; ++j)
        spatial[l + j * 64] = w[k0 * 256 + l + j * 64];
    float inv_s2 = 1.0f / best;
    for (int k = 0; k < K_; ++k) {
        float d = 0.0f;
#pragma unroll
        for (int j = 0; j < 4; ++j)
            d = fmaf(w[k * 256 + l + j * 64], w[k0 * 256 + l + j * 64], d);
        d = wave_sum(d);
        if (l == 0) temporal[k] = d * inv_s2;
    }
}

// ---------------------------------------------------------------------------
// Kernel 1: y[n, t] = sum_p x_patch[t, n, p] * spatial[p]
//
// One wave per (neuron, frame-pair). Grid is 1D, NCH*200 blocks, swizzled so
// each XCD owns a contiguous 50-frame range and, within an XCD, consecutive
// blocks sweep all neuron-chunks of ONE frame-pair -> each frame is filled
// into exactly one XCD L2 exactly once; the ~4x RF spatial overlap is
// absorbed in-L2 instead of re-fetched from HBM.
//
// Lane l covers pixels (r0 + i*4 + (l>>4), c0 + (l&15)), i = 0..3 -> each
// wave-load = 4 contiguous 64B row segments. Border RFs via predication.
// ---------------------------------------------------------------------------
__global__ __launch_bounds__(256) void stage1_kernel(
    const float* __restrict__ x, const int* __restrict__ rf,
    const float* __restrict__ spatial, float* __restrict__ y,
    int N, int NCH)
{
    int lane = threadIdx.x & 63;
    int wid  = threadIdx.x >> 6;

    // swizzle: f in [0, 8*25*NCH). xcd = f&7 owns t-pairs [xcd*25, xcd*25+25);
    // consecutive `local` on one XCD share the frame-pair (nch varies fastest).
    int f     = blockIdx.x;
    int xcd   = f & (NXCD - 1);
    int local = f >> 3;
    int tp    = xcd * TP_PER_XCD + local / NCH;
    int nch   = local % NCH;

    int n = nch * 4 + wid;
    if (n >= N) return;
    int t = tp * 2;

    int base = rf[n * 256];          // = v*PW + h (first padded index)
    int r0 = base / PW - RF_;        // top row in unpadded frame (may be <0)
    int c0 = base % PW - RF_;        // left col (may be <0)

    float w0 = spatial[lane];
    float w1 = spatial[lane + 64];
    float w2 = spatial[lane + 128];
    float w3 = spatial[lane + 192];

    int dx = lane & 15;
    int dy = lane >> 4;
    int c = c0 + dx;
    bool cok = (c >= 0) & (c < W_);

    int  ridx[4];
    bool ok[4];
#pragma unroll
    for (int i = 0; i < 4; ++i) {
        int r = r0 + i * 4 + dy;
        ok[i]   = cok & (r >= 0) & (r < H_);
        ridx[i] = r * W_ + c;
    }

    const float* xa = x + (size_t)t * (H_ * W_);
    const float* xb = xa + (size_t)(H_ * W_);
    float acca = 0.0f, accb = 0.0f;
#pragma unroll
    for (int i = 0; i < 4; ++i) {
        float wv = (i == 0) ? w0 : (i == 1) ? w1 : (i == 2) ? w2 : w3;
        float va = ok[i] ? xa[ridx[i]] : 0.0f;
        float vb = ok[i] ? xb[ridx[i]] : 0.0f;
        acca = fmaf(va, wv, acca);
        accb = fmaf(vb, wv, accb);
    }
#pragma unroll
    for (int off = 1; off < 64; off <<= 1) {
        acca += __shfl_xor(acca, off, 64);
        accb += __shfl_xor(accb, off, 64);
    }
    if (lane == 0) {
        y[n * T_ + t]     = acca;
        y[n * T_ + t + 1] = accb;
    }
}

// ---------------------------------------------------------------------------
// Kernel 2: out[n, t0] = ALPHA * softplus(BETA * (sum_k y[n,t0+k]*temporal[k]
//                                                  - GAMMA))
// ---------------------------------------------------------------------------
__global__ void stage2_kernel(const float* __restrict__ y,
                              const float* __restrict__ temporal,
                              float* __restrict__ out, int N)
{
    __shared__ float tw[K_];
    if (threadIdx.x < K_) tw[threadIdx.x] = temporal[threadIdx.x];
    __syncthreads();

    int n  = blockIdx.x;
    int t0 = threadIdx.x;
    if (n >= N || t0 >= NWIN) return;

    const float* yn = y + n * T_;
    float g = 0.0f;
#pragma unroll
    for (int k = 0; k < K_; ++k)
        g = fmaf(yn[t0 + k], tw[k], g);

    float z = BETA * (g - GAMMA);
    float sp = fmaxf(z, 0.0f) + log1pf(expf(-fabsf(z)));
    out[n * NWIN + t0] = ALPHA * sp;
}

// ---------------------------------------------------------------------------
extern "C" void kernel_launch(void* const* d_in, const int* in_sizes, int n_in,
                              void* d_out, int out_size, void* d_ws, size_t ws_size,
                              hipStream_t stream)
{
    const float* x  = (const float*)d_in[0];  // (T, H, W) f32
    const float* w  = (const float*)d_in[1];  // (K*RF*RF,) f32
    const int*   rf = (const int*)d_in[2];    // (N, 256) i32

    int N   = in_sizes[2] / (RF_ * RF_);
    int NCH = (N + 3) / 4;                    // 4 neurons (waves) per block

    float* spatial  = (float*)d_ws;           // 256
    float* temporal = spatial + 256;          // 20 (pad to 512)
    float* y        = spatial + 512;          // N * T

    factorize_kernel<<<1, 64, 0, stream>>>(w, spatial, temporal);
    stage1_kernel<<<NCH * TPAIRS, 256, 0, stream>>>(x, rf, spatial, y, N, NCH);
    stage2_kernel<<<N, 384, 0, stream>>>(y, temporal, (float*)d_out, N);
}

// Round 3
// 57.813 us; speedup vs baseline: 2.0739x; 1.0791x over previous
//
#include <hip/hip_runtime.h>
#include <math.h>

constexpr int H_ = 180, W_ = 320, RF_ = 16, K_ = 20, T_ = 400;
constexpr int HW_ = H_ * W_;
constexpr int NWIN = T_ - K_ + 1;   // 381
constexpr int PW   = W_ + 2 * RF_;  // 352 (padded width used by rf_indices)
constexpr float ALPHA = 50.0f, BETA = 1.0f, GAMMA = 0.0f;
constexpr int NXCD = 8;
constexpr int T_PER_XCD = T_ / NXCD;   // 50 frames per XCD

__device__ inline float wave_sum(float v) {
#pragma unroll
    for (int off = 1; off < 64; off <<= 1)
        v += __shfl_xor(v, off, 64);
    return v;
}

// ---------------------------------------------------------------------------
// Kernel 0: factorize w (K x 256) into temporal[K] (x) spatial[256].
// w is an exact rank-1 outer product (temporal ⊗ spatial / norm); LS-project
// onto the largest row. Single 64-thread block; negligible.
// ---------------------------------------------------------------------------
__global__ void factorize_kernel(const float* __restrict__ w,
                                 float* __restrict__ spatial,   // 256
                                 float* __restrict__ temporal)  // K
{
    int l = threadIdx.x;  // 0..63
    float best = -1.0f;
    int k0 = 0;
    for (int k = 0; k < K_; ++k) {
        float s = 0.0f;
#pragma unroll
        for (int j = 0; j < 4; ++j) {
            float v = w[k * 256 + l + j * 64];
            s = fmaf(v, v, s);
        }
        s = wave_sum(s);
        if (s > best) { best = s; k0 = k; }
    }
#pragma unroll
    for (int j = 0; j < 4; ++j)
        spatial[l + j * 64] = w[k0 * 256 + l + j * 64];
    float inv_s2 = 1.0f / best;
    for (int k = 0; k < K_; ++k) {
        float d = 0.0f;
#pragma unroll
        for (int j = 0; j < 4; ++j)
            d = fmaf(w[k * 256 + l + j * 64], w[k0 * 256 + l + j * 64], d);
        d = wave_sum(d);
        if (l == 0) temporal[k] = d * inv_s2;
    }
}

// ---------------------------------------------------------------------------
// Kernel 1: y[n, t] = sum_p x_patch[t, n, p] * spatial[p]
//
// Grid = NXCD * NCH blocks (1800 for N=900), ALL co-resident (7 blocks/CU at
// 16 VGPR). Block b -> XCD (b&7) owns frames [xcd*50, xcd*50+50); all ~225
// blocks (= all neurons) of one XCD sweep that range in lockstep, so each
// 230 KB frame is pulled into the XCD L2 once and the ~4x RF overlap is
// absorbed in-L2. Setup (rf decode, predication, addresses) is done ONCE per
// wave and amortized over 50 frames.
//
// Border handling hoisted out of the t-loop: clamp the gather index to 0 and
// zero the per-lane WEIGHT instead of predicating loads.
// ---------------------------------------------------------------------------
__global__ __launch_bounds__(256) void stage1_kernel(
    const float* __restrict__ x, const int* __restrict__ rf,
    const float* __restrict__ spatial, float* __restrict__ y,
    int N)
{
    int lane = threadIdx.x & 63;
    int wid  = threadIdx.x >> 6;

    int b   = blockIdx.x;
    int xcd = b & (NXCD - 1);
    int nch = b >> 3;

    int n = nch * 4 + wid;
    if (n >= N) return;
    int t0 = xcd * T_PER_XCD;

    int base = rf[n * 256];          // = v*PW + h (first padded index)
    int r0 = base / PW - RF_;        // top row in unpadded frame (may be <0)
    int c0 = base % PW - RF_;        // left col (may be <0)

    int dx = lane & 15;
    int dy = lane >> 4;
    int c = c0 + dx;
    bool cok = (c >= 0) & (c < W_);

    // per-lane gather indices + masked weights (frame-independent)
    int   ridx[4];
    float wv[4];
#pragma unroll
    for (int i = 0; i < 4; ++i) {
        int r = r0 + i * 4 + dy;
        bool ok = cok & (r >= 0) & (r < H_);
        ridx[i] = ok ? (r * W_ + c) : 0;
        wv[i]   = ok ? spatial[lane + i * 64] : 0.0f;
    }

    const float* xp = x + (size_t)t0 * HW_;
    float* yp = y + (size_t)n * T_ + t0;

    for (int tt = 0; tt < T_PER_XCD; tt += 2) {
        const float* xa = xp + (size_t)tt * HW_;
        const float* xb = xa + HW_;
        float acca = 0.0f, accb = 0.0f;
#pragma unroll
        for (int i = 0; i < 4; ++i) {
            float va = xa[ridx[i]];
            float vb = xb[ridx[i]];
            acca = fmaf(va, wv[i], acca);
            accb = fmaf(vb, wv[i], accb);
        }
#pragma unroll
        for (int off = 1; off < 64; off <<= 1) {
            acca += __shfl_xor(acca, off, 64);
            accb += __shfl_xor(accb, off, 64);
        }
        if (lane == 0) {
            yp[tt]     = acca;
            yp[tt + 1] = accb;
        }
    }
}

// ---------------------------------------------------------------------------
// Kernel 2: out[n, t0] = ALPHA * softplus(BETA * (sum_k y[n,t0+k]*temporal[k]
//                                                  - GAMMA))
// ---------------------------------------------------------------------------
__global__ void stage2_kernel(const float* __restrict__ y,
                              const float* __restrict__ temporal,
                              float* __restrict__ out, int N)
{
    __shared__ float tw[K_];
    if (threadIdx.x < K_) tw[threadIdx.x] = temporal[threadIdx.x];
    __syncthreads();

    int n  = blockIdx.x;
    int t0 = threadIdx.x;
    if (n >= N || t0 >= NWIN) return;

    const float* yn = y + (size_t)n * T_;
    float g = 0.0f;
#pragma unroll
    for (int k = 0; k < K_; ++k)
        g = fmaf(yn[t0 + k], tw[k], g);

    float z = BETA * (g - GAMMA);
    float sp = fmaxf(z, 0.0f) + log1pf(expf(-fabsf(z)));
    out[n * NWIN + t0] = ALPHA * sp;
}

// ---------------------------------------------------------------------------
extern "C" void kernel_launch(void* const* d_in, const int* in_sizes, int n_in,
                              void* d_out, int out_size, void* d_ws, size_t ws_size,
                              hipStream_t stream)
{
    const float* x  = (const float*)d_in[0];  // (T, H, W) f32
    const float* w  = (const float*)d_in[1];  // (K*RF*RF,) f32
    const int*   rf = (const int*)d_in[2];    // (N, 256) i32

    int N   = in_sizes[2] / (RF_ * RF_);
    int NCH = (N + 3) / 4;                    // 4 neurons (waves) per block

    float* spatial  = (float*)d_ws;           // 256
    float* temporal = spatial + 256;          // 20 (pad to 512)
    float* y        = spatial + 512;          // N * T

    factorize_kernel<<<1, 64, 0, stream>>>(w, spatial, temporal);
    stage1_kernel<<<NXCD * NCH, 256, 0, stream>>>(x, rf, spatial, y, N);
    stage2_kernel<<<N, 384, 0, stream>>>(y, temporal, (float*)d_out, N);
}